// Round 7
// baseline (954.051 us; speedup 1.0000x reference)
//
#include <hip/hip_runtime.h>

// ---------------------------------------------------------------------------
// GCN 2-layer: out = A_n @ relu(A_n @ (x W1) + b1) W2 + b2,  A_n = D^-1/2 A D^-1/2
// N=50000 nodes, E=800000 edges (+ implicit self loops), F: 128 -> 128 -> 64.
// CSR by dst (count -> scan -> fill), dense fp32 GEMMs, wave-per-node gather:
//   out_v = d_v*(sum_e d_s h_s + d_v h_v) + b
// R4: unbounded unroll -> 256 VGPR spill (2.3GB fetch). R5: no VGPR cap ->
//   2 waves/SIMD + 391 blocks -> 1.5 waves/SIMD avg, VALUBusy 13%.
// R6: profile showed impossible counters (30ms agg w/ VGPR=12, 1.6GB gemm
//   traffic, unchanged code) -> suspected device interference; re-measuring.
// R7 design: BM=64 -> 782 blocks both gemms, full-BN tiles (no A re-read),
//   TM=4, launch_bounds(256,4) caps VGPR<=128. dinv folded into scan1.
// ---------------------------------------------------------------------------

#define N_NODES 50000
#define N_EDGES 800000

// workspace layout (bytes, all 256-aligned)
static constexpr size_t OFF_DEG  = 0;         // int[50000]
static constexpr size_t OFF_CUR  = 200192;    // int[50000]
static constexpr size_t OFF_ROW  = 400384;    // int[50001]
static constexpr size_t OFF_BS   = 600576;    // int[256]
static constexpr size_t OFF_DINV = 601600;    // float[50000]
static constexpr size_t OFF_CSR  = 801792;    // int[800000]
static constexpr size_t OFF_H1   = 4001792;   // float[50000*128]  (reused as h2)
static constexpr size_t OFF_OUT1 = 29601792;  // float[50000*128]
// total ~55.2 MB

__global__ __launch_bounds__(256) void count_deg_k(const int* __restrict__ ei,
                                                   int* __restrict__ deg) {
    int e = blockIdx.x * 256 + threadIdx.x;
    if (e < N_EDGES) {
        int d = ei[N_EDGES + e];
        if ((unsigned)d < N_NODES) atomicAdd(&deg[d], 1);
    }
}

// block-scan of deg -> row_start (exclusive within block) + per-block sums;
// also emits dinv = rsqrt(deg+1) (self-loop folded analytically later).
__global__ __launch_bounds__(256) void scan1_k(const int* __restrict__ deg,
                                               int* __restrict__ row_start,
                                               int* __restrict__ bsums,
                                               float* __restrict__ dinv) {
    __shared__ int sm[256];
    int tid = threadIdx.x;
    int i = blockIdx.x * 256 + tid;
    int v = (i < N_NODES) ? deg[i] : 0;
    if (i < N_NODES) dinv[i] = rsqrtf((float)(v + 1));
    sm[tid] = v;
    __syncthreads();
    #pragma unroll
    for (int off = 1; off < 256; off <<= 1) {
        int t = (tid >= off) ? sm[tid - off] : 0;
        __syncthreads();
        sm[tid] += t;
        __syncthreads();
    }
    if (i < N_NODES) row_start[i] = sm[tid] - v;
    if (tid == 255) bsums[blockIdx.x] = sm[255];
}

__global__ __launch_bounds__(256) void scan2_k(int* __restrict__ bsums, int nb) {
    __shared__ int sm[256];
    int tid = threadIdx.x;
    int v = (tid < nb) ? bsums[tid] : 0;
    sm[tid] = v;
    __syncthreads();
    #pragma unroll
    for (int off = 1; off < 256; off <<= 1) {
        int t = (tid >= off) ? sm[tid - off] : 0;
        __syncthreads();
        sm[tid] += t;
        __syncthreads();
    }
    if (tid < nb) bsums[tid] = sm[tid] - v;  // exclusive block offsets
}

__global__ __launch_bounds__(256) void scan3_k(int* __restrict__ row_start,
                                               const int* __restrict__ bsums) {
    int i = blockIdx.x * 256 + threadIdx.x;
    if (i < N_NODES) row_start[i] += bsums[blockIdx.x];
    if (i == 0) row_start[N_NODES] = N_EDGES;
}

__global__ __launch_bounds__(256) void fill_k(const int* __restrict__ ei,
                                              const int* __restrict__ row_start,
                                              int* __restrict__ cursor,
                                              int* __restrict__ csr_src) {
    int e = blockIdx.x * 256 + threadIdx.x;
    if (e < N_EDGES) {
        int s = ei[e];
        int d = ei[N_EDGES + e];
        if ((unsigned)d < N_NODES && (unsigned)s < N_NODES) {
            int pos = row_start[d] + atomicAdd(&cursor[d], 1);
            if ((unsigned)pos < N_EDGES) csr_src[pos] = s;
        }
    }
}

// ---------------------------------------------------------------------------
// fp32 GEMM: C[M][N] = A[M][128] * B[128][N], full-N tile per block.
// BM=64 (782 blocks), BK=16, 256 threads, micro-tile TM=4 x TN.
// Double-buffered LDS, one barrier per K-step. launch_bounds(256,4): VGPR<=128.
// ---------------------------------------------------------------------------
template <int N, int TN>
__global__ __launch_bounds__(256, 4) void gemm_k(const float* __restrict__ A,
                                                 const float* __restrict__ B,
                                                 float* __restrict__ C, int M) {
    constexpr int K = 128, BK = 16, BM = 64, TM = 4;
    constexpr int NT = K / BK;            // 8 K-tiles
    constexpr int BPT = BK * N / 1024;    // B float4 loads/thread: 2 or 1

    __shared__ float AsT[2][BK][BM + 4];
    __shared__ float Bs[2][BK][N];

    const int tid = threadIdx.x;
    const int tx = tid & 15, ty = tid >> 4;
    const int m0 = ty * TM, n0 = tx * TN;
    const int blockM = blockIdx.x * BM;

    const int arow = tid >> 2;          // 0..63
    const int akq  = (tid & 3) * 4;     // k-quad

    int r = blockM + arow;
    r = r < M ? r : M - 1;
    const float* Aptr = A + (size_t)r * K + akq;

    float4 aS, bS[BPT];
    float acc[TM][TN] = {};

    auto gload = [&](int kt) {
        aS = *(const float4*)&Aptr[kt * BK];
        if constexpr (BPT == 2) {
            int bk = tid >> 5, bq = (tid & 31) * 4;
            bS[0] = *(const float4*)&B[(size_t)(kt * BK + bk) * N + bq];
            bS[1] = *(const float4*)&B[(size_t)(kt * BK + bk + 8) * N + bq];
        } else {
            int bk = tid >> 4, bq = (tid & 15) * 4;
            bS[0] = *(const float4*)&B[(size_t)(kt * BK + bk) * N + bq];
        }
    };
    auto lstore = [&](int buf) {
        AsT[buf][akq + 0][arow] = aS.x;
        AsT[buf][akq + 1][arow] = aS.y;
        AsT[buf][akq + 2][arow] = aS.z;
        AsT[buf][akq + 3][arow] = aS.w;
        if constexpr (BPT == 2) {
            int bk = tid >> 5, bq = (tid & 31) * 4;
            *(float4*)&Bs[buf][bk][bq] = bS[0];
            *(float4*)&Bs[buf][bk + 8][bq] = bS[1];
        } else {
            int bk = tid >> 4, bq = (tid & 15) * 4;
            *(float4*)&Bs[buf][bk][bq] = bS[0];
        }
    };
    auto compute = [&](int buf) {
        #pragma unroll
        for (int k = 0; k < BK; ++k) {
            float a[TM], b[TN];
            float4 ta = *(const float4*)&AsT[buf][k][m0];
            a[0] = ta.x; a[1] = ta.y; a[2] = ta.z; a[3] = ta.w;
            #pragma unroll
            for (int j = 0; j < TN; j += 4) {
                float4 tb = *(const float4*)&Bs[buf][k][n0 + j];
                b[j] = tb.x; b[j + 1] = tb.y; b[j + 2] = tb.z; b[j + 3] = tb.w;
            }
            #pragma unroll
            for (int i = 0; i < TM; ++i)
                #pragma unroll
                for (int j = 0; j < TN; ++j)
                    acc[i][j] = fmaf(a[i], b[j], acc[i][j]);
        }
    };

    gload(0); lstore(0);
    __syncthreads();
    #pragma unroll 2
    for (int kt = 0; kt < NT; ++kt) {
        if (kt + 1 < NT) gload(kt + 1);
        compute(kt & 1);
        if (kt + 1 < NT) {
            // safe: buf^1's readers all passed the previous barrier already
            lstore((kt + 1) & 1);
            __syncthreads();
        }
    }

    #pragma unroll
    for (int i = 0; i < TM; ++i) {
        int row = blockM + m0 + i;
        if (row < M) {
            #pragma unroll
            for (int j = 0; j < TN; j += 4) {
                *(float4*)&C[(size_t)row * N + n0 + j] =
                    make_float4(acc[i][j], acc[i][j + 1], acc[i][j + 2], acc[i][j + 3]);
            }
        }
    }
}

// ---------------------------------------------------------------------------
// Aggregation: one wave (64 lanes) per node.
// F=128: lane holds float2; F=64: lane holds float.
// out_v = d_v * (sum_edges d_s * h_s + d_v * h_v) + bias  [, relu]
// ---------------------------------------------------------------------------
template <int F, bool RELU>
__global__ __launch_bounds__(256) void agg_k(const float* __restrict__ h,
                                             const float* __restrict__ dinv,
                                             const int* __restrict__ row_start,
                                             const int* __restrict__ csr_src,
                                             const float* __restrict__ bias,
                                             float* __restrict__ out) {
    constexpr int VEC = F / 64;  // 2 or 1
    int wid = (blockIdx.x * 256 + threadIdx.x) >> 6;
    int lane = threadIdx.x & 63;
    if (wid >= N_NODES) return;
    int v = wid;
    float dv = dinv[v];

    float acc0, acc1 = 0.f;
    const float* hv = h + (size_t)v * F;
    if constexpr (VEC == 2) {
        float2 t = *(const float2*)&hv[lane * 2];
        acc0 = dv * t.x; acc1 = dv * t.y;
    } else {
        acc0 = dv * hv[lane];
    }

    int e0 = row_start[v], e1 = row_start[v + 1];
    for (int e = e0; e < e1; e += 64) {
        int cnt = min(64, e1 - e);
        int s = 0; float w = 0.f;
        if (lane < cnt) { s = csr_src[e + lane]; w = dinv[s]; }
        for (int j = 0; j < cnt; ++j) {
            int ss = __shfl(s, j);
            float ww = __shfl(w, j);
            const float* hs = h + (size_t)ss * F;
            if constexpr (VEC == 2) {
                float2 t = *(const float2*)&hs[lane * 2];
                acc0 = fmaf(ww, t.x, acc0); acc1 = fmaf(ww, t.y, acc1);
            } else {
                acc0 = fmaf(ww, hs[lane], acc0);
            }
        }
    }

    if constexpr (VEC == 2) {
        float o0 = dv * acc0 + bias[lane * 2];
        float o1 = dv * acc1 + bias[lane * 2 + 1];
        if (RELU) { o0 = fmaxf(o0, 0.f); o1 = fmaxf(o1, 0.f); }
        *(float2*)&out[(size_t)v * F + lane * 2] = make_float2(o0, o1);
    } else {
        float o0 = dv * acc0 + bias[lane];
        if (RELU) o0 = fmaxf(o0, 0.f);
        out[(size_t)v * F + lane] = o0;
    }
}

extern "C" void kernel_launch(void* const* d_in, const int* in_sizes, int n_in,
                              void* d_out, int out_size, void* d_ws, size_t ws_size,
                              hipStream_t stream) {
    const float* x        = (const float*)d_in[0];   // [50000,128]
    const float* W1       = (const float*)d_in[1];   // [128,128]
    const float* b1       = (const float*)d_in[2];   // [128]
    const float* W2       = (const float*)d_in[3];   // [128,64]
    const float* b2       = (const float*)d_in[4];   // [64]
    const int*   ei       = (const int*)d_in[5];     // [2,800000] delivered as int32
    float* out = (float*)d_out;                      // [50000,64]

    char* ws = (char*)d_ws;
    int*   deg       = (int*)(ws + OFF_DEG);
    int*   cursor    = (int*)(ws + OFF_CUR);
    int*   row_start = (int*)(ws + OFF_ROW);
    int*   bsums     = (int*)(ws + OFF_BS);
    float* dinv      = (float*)(ws + OFF_DINV);
    int*   csr_src   = (int*)(ws + OFF_CSR);
    float* h1        = (float*)(ws + OFF_H1);
    float* out1      = (float*)(ws + OFF_OUT1);
    float* h2        = (float*)(ws + OFF_H1);  // reuse: h1 dead after agg1

    // zero deg + cursor
    hipMemsetAsync(ws + OFF_DEG, 0, OFF_ROW - OFF_DEG, stream);

    const int nbE = (N_EDGES + 255) / 256;   // 3125
    const int nbN = (N_NODES + 255) / 256;   // 196

    count_deg_k<<<nbE, 256, 0, stream>>>(ei, deg);
    scan1_k<<<nbN, 256, 0, stream>>>(deg, row_start, bsums, dinv);
    scan2_k<<<1, 256, 0, stream>>>(bsums, nbN);
    scan3_k<<<nbN, 256, 0, stream>>>(row_start, bsums);
    fill_k<<<nbE, 256, 0, stream>>>(ei, row_start, cursor, csr_src);

    const int gemmBlocks = (N_NODES + 63) / 64;  // 782
    gemm_k<128, 8><<<gemmBlocks, 256, 0, stream>>>(x, W1, h1, N_NODES);
    agg_k<128, true><<<(N_NODES + 3) / 4, 256, 0, stream>>>(h1, dinv, row_start, csr_src, b1, out1);
    gemm_k<64, 4><<<gemmBlocks, 256, 0, stream>>>(out1, W2, h2, N_NODES);
    agg_k<64, false><<<(N_NODES + 3) / 4, 256, 0, stream>>>(h2, dinv, row_start, csr_src, b2, out);
}

// Round 8
// 269.602 us; speedup vs baseline: 3.5387x; 3.5387x over previous
//
#include <hip/hip_runtime.h>

// ---------------------------------------------------------------------------
// GCN 2-layer: out = A_n @ relu(A_n @ (x W1) + b1) W2 + b2,  A_n = D^-1/2 A D^-1/2
// N=50000 nodes, E=800000 edges (+ implicit self loops), F: 128 -> 128 -> 64.
// CSR by dst (count -> scan -> fill), dense fp32 GEMMs, wave-per-node gather:
//   out_v = d_v*(sum_e d_s h_s + d_v h_v) + b
// R4: unroll spill (2.3GB). R5: no VGPR cap, 8% occ. R6/R7: LDS-staged dbuf
//   GEMM shows reproducible 40x write inflation (1.03GB writes, VALUBusy 2%)
//   -> abandon staging pipeline entirely.
// R8 design: W fits in LDS! Load B once per block (34KB), one barrier, then
//   stream A rows direct from global (float4, L1 broadcast reuse), 4x4 acc.
//   No A-LDS, no double-buffer, no K-loop barriers, no lambdas. ~50 VGPR.
// ---------------------------------------------------------------------------

#define N_NODES 50000
#define N_EDGES 800000

// workspace layout (bytes, all 256-aligned)
static constexpr size_t OFF_DEG  = 0;         // int[50000]
static constexpr size_t OFF_CUR  = 200192;    // int[50000]
static constexpr size_t OFF_ROW  = 400384;    // int[50001]
static constexpr size_t OFF_BS   = 600576;    // int[256]
static constexpr size_t OFF_DINV = 601600;    // float[50000]
static constexpr size_t OFF_CSR  = 801792;    // int[800000]
static constexpr size_t OFF_H1   = 4001792;   // float[50000*128]  (reused as h2)
static constexpr size_t OFF_OUT1 = 29601792;  // float[50000*128]
// total ~55.2 MB

__global__ __launch_bounds__(256) void count_deg_k(const int* __restrict__ ei,
                                                   int* __restrict__ deg) {
    int e = blockIdx.x * 256 + threadIdx.x;
    if (e < N_EDGES) {
        int d = ei[N_EDGES + e];
        if ((unsigned)d < N_NODES) atomicAdd(&deg[d], 1);
    }
}

// block-scan of deg -> row_start + per-block sums; also emits dinv.
__global__ __launch_bounds__(256) void scan1_k(const int* __restrict__ deg,
                                               int* __restrict__ row_start,
                                               int* __restrict__ bsums,
                                               float* __restrict__ dinv) {
    __shared__ int sm[256];
    int tid = threadIdx.x;
    int i = blockIdx.x * 256 + tid;
    int v = (i < N_NODES) ? deg[i] : 0;
    if (i < N_NODES) dinv[i] = rsqrtf((float)(v + 1));
    sm[tid] = v;
    __syncthreads();
    #pragma unroll
    for (int off = 1; off < 256; off <<= 1) {
        int t = (tid >= off) ? sm[tid - off] : 0;
        __syncthreads();
        sm[tid] += t;
        __syncthreads();
    }
    if (i < N_NODES) row_start[i] = sm[tid] - v;
    if (tid == 255) bsums[blockIdx.x] = sm[255];
}

__global__ __launch_bounds__(256) void scan2_k(int* __restrict__ bsums, int nb) {
    __shared__ int sm[256];
    int tid = threadIdx.x;
    int v = (tid < nb) ? bsums[tid] : 0;
    sm[tid] = v;
    __syncthreads();
    #pragma unroll
    for (int off = 1; off < 256; off <<= 1) {
        int t = (tid >= off) ? sm[tid - off] : 0;
        __syncthreads();
        sm[tid] += t;
        __syncthreads();
    }
    if (tid < nb) bsums[tid] = sm[tid] - v;  // exclusive block offsets
}

__global__ __launch_bounds__(256) void scan3_k(int* __restrict__ row_start,
                                               const int* __restrict__ bsums) {
    int i = blockIdx.x * 256 + threadIdx.x;
    if (i < N_NODES) row_start[i] += bsums[blockIdx.x];
    if (i == 0) row_start[N_NODES] = N_EDGES;
}

__global__ __launch_bounds__(256) void fill_k(const int* __restrict__ ei,
                                              const int* __restrict__ row_start,
                                              int* __restrict__ cursor,
                                              int* __restrict__ csr_src) {
    int e = blockIdx.x * 256 + threadIdx.x;
    if (e < N_EDGES) {
        int s = ei[e];
        int d = ei[N_EDGES + e];
        if ((unsigned)d < N_NODES && (unsigned)s < N_NODES) {
            int pos = row_start[d] + atomicAdd(&cursor[d], 1);
            if ((unsigned)pos < N_EDGES) csr_src[pos] = s;
        }
    }
}

// ---------------------------------------------------------------------------
// fp32 GEMM with whole-B-in-LDS. C[M][N] = A[M][128] * B[128][N].
// Block: 256 threads, BM=64 rows x BN=64 cols. grid = (ceil(M/64), N/64).
// LDS: Bs[128][68] = 34KB (one-time cooperative load, single barrier).
// Thread (tx,ty): 4x4 acc at rows ty*4.., cols tx*4..; A read direct from
// global as float4 (16-lane broadcast within wave -> L1-served reuse).
// ---------------------------------------------------------------------------
template <int N>
__global__ __launch_bounds__(256, 4) void gemm_blds(const float* __restrict__ A,
                                                    const float* __restrict__ B,
                                                    float* __restrict__ C, int M) {
    constexpr int K = 128, BM = 64, BN = 64, PAD = 4;
    __shared__ float Bs[K][BN + PAD];   // 34816 B

    const int tid = threadIdx.x;
    const int nBase = blockIdx.y * BN;

    // cooperative B load: 128x64 floats = 2048 float4 / 256 thr = 8 each
    #pragma unroll
    for (int p = 0; p < 8; ++p) {
        int fi = tid + p * 256;
        int row = fi >> 4;            // 0..127
        int c4 = (fi & 15) * 4;       // 0..60
        float4 t = *(const float4*)&B[(size_t)row * N + nBase + c4];
        *(float4*)&Bs[row][c4] = t;
    }
    __syncthreads();

    const int tx = tid & 15, ty = tid >> 4;
    const int m0 = blockIdx.x * BM + ty * 4;
    const int n0 = tx * 4;

    const float* A0 = A + (size_t)(m0 + 0 < M ? m0 + 0 : M - 1) * K;
    const float* A1 = A + (size_t)(m0 + 1 < M ? m0 + 1 : M - 1) * K;
    const float* A2 = A + (size_t)(m0 + 2 < M ? m0 + 2 : M - 1) * K;
    const float* A3 = A + (size_t)(m0 + 3 < M ? m0 + 3 : M - 1) * K;

    float acc[4][4] = {};

    #pragma unroll 4
    for (int kq = 0; kq < K / 4; ++kq) {        // 32 iterations, 4 k each
        float4 a0 = *(const float4*)&A0[kq * 4];
        float4 a1 = *(const float4*)&A1[kq * 4];
        float4 a2 = *(const float4*)&A2[kq * 4];
        float4 a3 = *(const float4*)&A3[kq * 4];
        #pragma unroll
        for (int kk = 0; kk < 4; ++kk) {
            int k = kq * 4 + kk;
            float4 bv = *(const float4*)&Bs[k][n0];
            float av0 = kk == 0 ? a0.x : kk == 1 ? a0.y : kk == 2 ? a0.z : a0.w;
            float av1 = kk == 0 ? a1.x : kk == 1 ? a1.y : kk == 2 ? a1.z : a1.w;
            float av2 = kk == 0 ? a2.x : kk == 1 ? a2.y : kk == 2 ? a2.z : a2.w;
            float av3 = kk == 0 ? a3.x : kk == 1 ? a3.y : kk == 2 ? a3.z : a3.w;
            acc[0][0] = fmaf(av0, bv.x, acc[0][0]);
            acc[0][1] = fmaf(av0, bv.y, acc[0][1]);
            acc[0][2] = fmaf(av0, bv.z, acc[0][2]);
            acc[0][3] = fmaf(av0, bv.w, acc[0][3]);
            acc[1][0] = fmaf(av1, bv.x, acc[1][0]);
            acc[1][1] = fmaf(av1, bv.y, acc[1][1]);
            acc[1][2] = fmaf(av1, bv.z, acc[1][2]);
            acc[1][3] = fmaf(av1, bv.w, acc[1][3]);
            acc[2][0] = fmaf(av2, bv.x, acc[2][0]);
            acc[2][1] = fmaf(av2, bv.y, acc[2][1]);
            acc[2][2] = fmaf(av2, bv.z, acc[2][2]);
            acc[2][3] = fmaf(av2, bv.w, acc[2][3]);
            acc[3][0] = fmaf(av3, bv.x, acc[3][0]);
            acc[3][1] = fmaf(av3, bv.y, acc[3][1]);
            acc[3][2] = fmaf(av3, bv.z, acc[3][2]);
            acc[3][3] = fmaf(av3, bv.w, acc[3][3]);
        }
    }

    #pragma unroll
    for (int i = 0; i < 4; ++i) {
        int row = blockIdx.x * BM + ty * 4 + i;
        if (row < M) {
            *(float4*)&C[(size_t)row * N + nBase + n0] =
                make_float4(acc[i][0], acc[i][1], acc[i][2], acc[i][3]);
        }
    }
}

// ---------------------------------------------------------------------------
// Aggregation: one wave (64 lanes) per node.
// out_v = d_v * (sum_edges d_s * h_s + d_v * h_v) + bias  [, relu]
// ---------------------------------------------------------------------------
template <int F, bool RELU>
__global__ __launch_bounds__(256) void agg_k(const float* __restrict__ h,
                                             const float* __restrict__ dinv,
                                             const int* __restrict__ row_start,
                                             const int* __restrict__ csr_src,
                                             const float* __restrict__ bias,
                                             float* __restrict__ out) {
    constexpr int VEC = F / 64;  // 2 or 1
    int wid = (blockIdx.x * 256 + threadIdx.x) >> 6;
    int lane = threadIdx.x & 63;
    if (wid >= N_NODES) return;
    int v = wid;
    float dv = dinv[v];

    float acc0, acc1 = 0.f;
    const float* hv = h + (size_t)v * F;
    if constexpr (VEC == 2) {
        float2 t = *(const float2*)&hv[lane * 2];
        acc0 = dv * t.x; acc1 = dv * t.y;
    } else {
        acc0 = dv * hv[lane];
    }

    int e0 = row_start[v], e1 = row_start[v + 1];
    for (int e = e0; e < e1; e += 64) {
        int cnt = min(64, e1 - e);
        int s = 0; float w = 0.f;
        if (lane < cnt) { s = csr_src[e + lane]; w = dinv[s]; }
        for (int j = 0; j < cnt; ++j) {
            int ss = __shfl(s, j);
            float ww = __shfl(w, j);
            const float* hs = h + (size_t)ss * F;
            if constexpr (VEC == 2) {
                float2 t = *(const float2*)&hs[lane * 2];
                acc0 = fmaf(ww, t.x, acc0); acc1 = fmaf(ww, t.y, acc1);
            } else {
                acc0 = fmaf(ww, hs[lane], acc0);
            }
        }
    }

    if constexpr (VEC == 2) {
        float o0 = dv * acc0 + bias[lane * 2];
        float o1 = dv * acc1 + bias[lane * 2 + 1];
        if (RELU) { o0 = fmaxf(o0, 0.f); o1 = fmaxf(o1, 0.f); }
        *(float2*)&out[(size_t)v * F + lane * 2] = make_float2(o0, o1);
    } else {
        float o0 = dv * acc0 + bias[lane];
        if (RELU) o0 = fmaxf(o0, 0.f);
        out[(size_t)v * F + lane] = o0;
    }
}

extern "C" void kernel_launch(void* const* d_in, const int* in_sizes, int n_in,
                              void* d_out, int out_size, void* d_ws, size_t ws_size,
                              hipStream_t stream) {
    const float* x        = (const float*)d_in[0];   // [50000,128]
    const float* W1       = (const float*)d_in[1];   // [128,128]
    const float* b1       = (const float*)d_in[2];   // [128]
    const float* W2       = (const float*)d_in[3];   // [128,64]
    const float* b2       = (const float*)d_in[4];   // [64]
    const int*   ei       = (const int*)d_in[5];     // [2,800000] delivered as int32
    float* out = (float*)d_out;                      // [50000,64]

    char* ws = (char*)d_ws;
    int*   deg       = (int*)(ws + OFF_DEG);
    int*   cursor    = (int*)(ws + OFF_CUR);
    int*   row_start = (int*)(ws + OFF_ROW);
    int*   bsums     = (int*)(ws + OFF_BS);
    float* dinv      = (float*)(ws + OFF_DINV);
    int*   csr_src   = (int*)(ws + OFF_CSR);
    float* h1        = (float*)(ws + OFF_H1);
    float* out1      = (float*)(ws + OFF_OUT1);
    float* h2        = (float*)(ws + OFF_H1);  // reuse: h1 dead after agg1

    // zero deg + cursor
    hipMemsetAsync(ws + OFF_DEG, 0, OFF_ROW - OFF_DEG, stream);

    const int nbE = (N_EDGES + 255) / 256;   // 3125
    const int nbN = (N_NODES + 255) / 256;   // 196

    count_deg_k<<<nbE, 256, 0, stream>>>(ei, deg);
    scan1_k<<<nbN, 256, 0, stream>>>(deg, row_start, bsums, dinv);
    scan2_k<<<1, 256, 0, stream>>>(bsums, nbN);
    scan3_k<<<nbN, 256, 0, stream>>>(row_start, bsums);
    fill_k<<<nbE, 256, 0, stream>>>(ei, row_start, cursor, csr_src);

    const int mBlocks = (N_NODES + 63) / 64;  // 782
    gemm_blds<128><<<dim3(mBlocks, 2), 256, 0, stream>>>(x, W1, h1, N_NODES);
    agg_k<128, true><<<(N_NODES + 3) / 4, 256, 0, stream>>>(h1, dinv, row_start, csr_src, b1, out1);
    gemm_blds<64><<<dim3(mBlocks, 1), 256, 0, stream>>>(out1, W2, h2, N_NODES);
    agg_k<64, false><<<(N_NODES + 3) / 4, 256, 0, stream>>>(h2, dinv, row_start, csr_src, b2, out);
}

// Round 9
// 244.153 us; speedup vs baseline: 3.9076x; 1.1042x over previous
//
#include <hip/hip_runtime.h>

// ---------------------------------------------------------------------------
// GCN 2-layer: out = A_n @ relu(A_n @ (x W1) + b1) W2 + b2,  A_n = D^-1/2 A D^-1/2
// N=50000 nodes, E=800000 edges (+ implicit self loops), F: 128 -> 128 -> 64.
// CSR by dst (count -> scan -> fill), dense fp32 GEMMs (B-in-LDS), wave-per-
// node gather:  out_v = d_v*(sum_e d_s h_s + d_v h_v) + b
// R4: unroll spill. R5: no VGPR cap. R6/R7: staged-LDS GEMM write inflation
//   -> replaced with whole-B-in-LDS GEMM (R8: GEMMs off the top-5).
// R8 profile: agg_k 68us each @ 3.2TB/s (50% BW), VALUBusy 17% -> gather
//   latency-bound, 1 load in flight (vmcnt(0) per edge iteration).
// R9: 4x unrolled edge loop -> 4 independent row-gathers in flight.
// ---------------------------------------------------------------------------

#define N_NODES 50000
#define N_EDGES 800000

// workspace layout (bytes, all 256-aligned)
static constexpr size_t OFF_DEG  = 0;         // int[50000]
static constexpr size_t OFF_CUR  = 200192;    // int[50000]
static constexpr size_t OFF_ROW  = 400384;    // int[50001]
static constexpr size_t OFF_BS   = 600576;    // int[256]
static constexpr size_t OFF_DINV = 601600;    // float[50000]
static constexpr size_t OFF_CSR  = 801792;    // int[800000]
static constexpr size_t OFF_H1   = 4001792;   // float[50000*128]  (reused as h2)
static constexpr size_t OFF_OUT1 = 29601792;  // float[50000*128]
// total ~55.2 MB

__global__ __launch_bounds__(256) void count_deg_k(const int* __restrict__ ei,
                                                   int* __restrict__ deg) {
    int e = blockIdx.x * 256 + threadIdx.x;
    if (e < N_EDGES) {
        int d = ei[N_EDGES + e];
        if ((unsigned)d < N_NODES) atomicAdd(&deg[d], 1);
    }
}

// block-scan of deg -> row_start + per-block sums; also emits dinv.
__global__ __launch_bounds__(256) void scan1_k(const int* __restrict__ deg,
                                               int* __restrict__ row_start,
                                               int* __restrict__ bsums,
                                               float* __restrict__ dinv) {
    __shared__ int sm[256];
    int tid = threadIdx.x;
    int i = blockIdx.x * 256 + tid;
    int v = (i < N_NODES) ? deg[i] : 0;
    if (i < N_NODES) dinv[i] = rsqrtf((float)(v + 1));
    sm[tid] = v;
    __syncthreads();
    #pragma unroll
    for (int off = 1; off < 256; off <<= 1) {
        int t = (tid >= off) ? sm[tid - off] : 0;
        __syncthreads();
        sm[tid] += t;
        __syncthreads();
    }
    if (i < N_NODES) row_start[i] = sm[tid] - v;
    if (tid == 255) bsums[blockIdx.x] = sm[255];
}

__global__ __launch_bounds__(256) void scan2_k(int* __restrict__ bsums, int nb) {
    __shared__ int sm[256];
    int tid = threadIdx.x;
    int v = (tid < nb) ? bsums[tid] : 0;
    sm[tid] = v;
    __syncthreads();
    #pragma unroll
    for (int off = 1; off < 256; off <<= 1) {
        int t = (tid >= off) ? sm[tid - off] : 0;
        __syncthreads();
        sm[tid] += t;
        __syncthreads();
    }
    if (tid < nb) bsums[tid] = sm[tid] - v;  // exclusive block offsets
}

__global__ __launch_bounds__(256) void scan3_k(int* __restrict__ row_start,
                                               const int* __restrict__ bsums) {
    int i = blockIdx.x * 256 + threadIdx.x;
    if (i < N_NODES) row_start[i] += bsums[blockIdx.x];
    if (i == 0) row_start[N_NODES] = N_EDGES;
}

__global__ __launch_bounds__(256) void fill_k(const int* __restrict__ ei,
                                              const int* __restrict__ row_start,
                                              int* __restrict__ cursor,
                                              int* __restrict__ csr_src) {
    int e = blockIdx.x * 256 + threadIdx.x;
    if (e < N_EDGES) {
        int s = ei[e];
        int d = ei[N_EDGES + e];
        if ((unsigned)d < N_NODES && (unsigned)s < N_NODES) {
            int pos = row_start[d] + atomicAdd(&cursor[d], 1);
            if ((unsigned)pos < N_EDGES) csr_src[pos] = s;
        }
    }
}

// ---------------------------------------------------------------------------
// fp32 GEMM with whole-B-in-LDS. C[M][N] = A[M][128] * B[128][N].
// Block: 256 threads, BM=64 rows x BN=64 cols. grid = (ceil(M/64), N/64).
// ---------------------------------------------------------------------------
template <int N>
__global__ __launch_bounds__(256, 4) void gemm_blds(const float* __restrict__ A,
                                                    const float* __restrict__ B,
                                                    float* __restrict__ C, int M) {
    constexpr int K = 128, BM = 64, BN = 64, PAD = 4;
    __shared__ float Bs[K][BN + PAD];   // 34816 B

    const int tid = threadIdx.x;
    const int nBase = blockIdx.y * BN;

    #pragma unroll
    for (int p = 0; p < 8; ++p) {
        int fi = tid + p * 256;
        int row = fi >> 4;            // 0..127
        int c4 = (fi & 15) * 4;       // 0..60
        float4 t = *(const float4*)&B[(size_t)row * N + nBase + c4];
        *(float4*)&Bs[row][c4] = t;
    }
    __syncthreads();

    const int tx = tid & 15, ty = tid >> 4;
    const int m0 = blockIdx.x * BM + ty * 4;
    const int n0 = tx * 4;

    const float* A0 = A + (size_t)(m0 + 0 < M ? m0 + 0 : M - 1) * K;
    const float* A1 = A + (size_t)(m0 + 1 < M ? m0 + 1 : M - 1) * K;
    const float* A2 = A + (size_t)(m0 + 2 < M ? m0 + 2 : M - 1) * K;
    const float* A3 = A + (size_t)(m0 + 3 < M ? m0 + 3 : M - 1) * K;

    float acc[4][4] = {};

    #pragma unroll 4
    for (int kq = 0; kq < K / 4; ++kq) {
        float4 a0 = *(const float4*)&A0[kq * 4];
        float4 a1 = *(const float4*)&A1[kq * 4];
        float4 a2 = *(const float4*)&A2[kq * 4];
        float4 a3 = *(const float4*)&A3[kq * 4];
        #pragma unroll
        for (int kk = 0; kk < 4; ++kk) {
            int k = kq * 4 + kk;
            float4 bv = *(const float4*)&Bs[k][n0];
            float av0 = kk == 0 ? a0.x : kk == 1 ? a0.y : kk == 2 ? a0.z : a0.w;
            float av1 = kk == 0 ? a1.x : kk == 1 ? a1.y : kk == 2 ? a1.z : a1.w;
            float av2 = kk == 0 ? a2.x : kk == 1 ? a2.y : kk == 2 ? a2.z : a2.w;
            float av3 = kk == 0 ? a3.x : kk == 1 ? a3.y : kk == 2 ? a3.z : a3.w;
            acc[0][0] = fmaf(av0, bv.x, acc[0][0]);
            acc[0][1] = fmaf(av0, bv.y, acc[0][1]);
            acc[0][2] = fmaf(av0, bv.z, acc[0][2]);
            acc[0][3] = fmaf(av0, bv.w, acc[0][3]);
            acc[1][0] = fmaf(av1, bv.x, acc[1][0]);
            acc[1][1] = fmaf(av1, bv.y, acc[1][1]);
            acc[1][2] = fmaf(av1, bv.z, acc[1][2]);
            acc[1][3] = fmaf(av1, bv.w, acc[1][3]);
            acc[2][0] = fmaf(av2, bv.x, acc[2][0]);
            acc[2][1] = fmaf(av2, bv.y, acc[2][1]);
            acc[2][2] = fmaf(av2, bv.z, acc[2][2]);
            acc[2][3] = fmaf(av2, bv.w, acc[2][3]);
            acc[3][0] = fmaf(av3, bv.x, acc[3][0]);
            acc[3][1] = fmaf(av3, bv.y, acc[3][1]);
            acc[3][2] = fmaf(av3, bv.z, acc[3][2]);
            acc[3][3] = fmaf(av3, bv.w, acc[3][3]);
        }
    }

    #pragma unroll
    for (int i = 0; i < 4; ++i) {
        int row = blockIdx.x * BM + ty * 4 + i;
        if (row < M) {
            *(float4*)&C[(size_t)row * N + nBase + n0] =
                make_float4(acc[i][0], acc[i][1], acc[i][2], acc[i][3]);
        }
    }
}

// ---------------------------------------------------------------------------
// Aggregation: one wave (64 lanes) per node; 4x-unrolled edge loop so 4
// independent row-gathers are in flight (R8 was 1 -> 50% BW).
// out_v = d_v * (sum_edges d_s * h_s + d_v * h_v) + bias  [, relu]
// ---------------------------------------------------------------------------
template <int F, bool RELU>
__global__ __launch_bounds__(256) void agg_k(const float* __restrict__ h,
                                             const float* __restrict__ dinv,
                                             const int* __restrict__ row_start,
                                             const int* __restrict__ csr_src,
                                             const float* __restrict__ bias,
                                             float* __restrict__ out) {
    constexpr int VEC = F / 64;  // 2 or 1
    int wid = (blockIdx.x * 256 + threadIdx.x) >> 6;
    int lane = threadIdx.x & 63;
    if (wid >= N_NODES) return;
    int v = wid;
    float dv = dinv[v];

    const float* hL = h + (size_t)lane * VEC;  // lane-offset base

    float acc0, acc1 = 0.f;
    {
        const float* hv = hL + (size_t)v * F;
        if constexpr (VEC == 2) {
            float2 t = *(const float2*)hv;
            acc0 = dv * t.x; acc1 = dv * t.y;
        } else {
            acc0 = dv * hv[0];
        }
    }

    int e0 = row_start[v], e1 = row_start[v + 1];
    for (int e = e0; e < e1; e += 64) {
        int cnt = min(64, e1 - e);
        int s = 0; float w = 0.f;
        if (lane < cnt) { s = csr_src[e + lane]; w = dinv[s]; }
        int j = 0;
        for (; j + 4 <= cnt; j += 4) {
            int   ss0 = __shfl(s, j + 0), ss1 = __shfl(s, j + 1),
                  ss2 = __shfl(s, j + 2), ss3 = __shfl(s, j + 3);
            float ww0 = __shfl(w, j + 0), ww1 = __shfl(w, j + 1),
                  ww2 = __shfl(w, j + 2), ww3 = __shfl(w, j + 3);
            if constexpr (VEC == 2) {
                float2 t0 = *(const float2*)&hL[(size_t)ss0 * F];
                float2 t1 = *(const float2*)&hL[(size_t)ss1 * F];
                float2 t2 = *(const float2*)&hL[(size_t)ss2 * F];
                float2 t3 = *(const float2*)&hL[(size_t)ss3 * F];
                acc0 = fmaf(ww0, t0.x, acc0); acc1 = fmaf(ww0, t0.y, acc1);
                acc0 = fmaf(ww1, t1.x, acc0); acc1 = fmaf(ww1, t1.y, acc1);
                acc0 = fmaf(ww2, t2.x, acc0); acc1 = fmaf(ww2, t2.y, acc1);
                acc0 = fmaf(ww3, t3.x, acc0); acc1 = fmaf(ww3, t3.y, acc1);
            } else {
                float t0 = hL[(size_t)ss0 * F];
                float t1 = hL[(size_t)ss1 * F];
                float t2 = hL[(size_t)ss2 * F];
                float t3 = hL[(size_t)ss3 * F];
                acc0 = fmaf(ww0, t0, acc0);
                acc0 = fmaf(ww1, t1, acc0);
                acc0 = fmaf(ww2, t2, acc0);
                acc0 = fmaf(ww3, t3, acc0);
            }
        }
        for (; j < cnt; ++j) {
            int ss = __shfl(s, j);
            float ww = __shfl(w, j);
            if constexpr (VEC == 2) {
                float2 t = *(const float2*)&hL[(size_t)ss * F];
                acc0 = fmaf(ww, t.x, acc0); acc1 = fmaf(ww, t.y, acc1);
            } else {
                acc0 = fmaf(ww, hL[(size_t)ss * F], acc0);
            }
        }
    }

    if constexpr (VEC == 2) {
        float o0 = dv * acc0 + bias[lane * 2];
        float o1 = dv * acc1 + bias[lane * 2 + 1];
        if (RELU) { o0 = fmaxf(o0, 0.f); o1 = fmaxf(o1, 0.f); }
        *(float2*)&out[(size_t)v * F + lane * 2] = make_float2(o0, o1);
    } else {
        float o0 = dv * acc0 + bias[lane];
        if (RELU) o0 = fmaxf(o0, 0.f);
        out[(size_t)v * F + lane] = o0;
    }
}

extern "C" void kernel_launch(void* const* d_in, const int* in_sizes, int n_in,
                              void* d_out, int out_size, void* d_ws, size_t ws_size,
                              hipStream_t stream) {
    const float* x        = (const float*)d_in[0];   // [50000,128]
    const float* W1       = (const float*)d_in[1];   // [128,128]
    const float* b1       = (const float*)d_in[2];   // [128]
    const float* W2       = (const float*)d_in[3];   // [128,64]
    const float* b2       = (const float*)d_in[4];   // [64]
    const int*   ei       = (const int*)d_in[5];     // [2,800000] delivered as int32
    float* out = (float*)d_out;                      // [50000,64]

    char* ws = (char*)d_ws;
    int*   deg       = (int*)(ws + OFF_DEG);
    int*   cursor    = (int*)(ws + OFF_CUR);
    int*   row_start = (int*)(ws + OFF_ROW);
    int*   bsums     = (int*)(ws + OFF_BS);
    float* dinv      = (float*)(ws + OFF_DINV);
    int*   csr_src   = (int*)(ws + OFF_CSR);
    float* h1        = (float*)(ws + OFF_H1);
    float* out1      = (float*)(ws + OFF_OUT1);
    float* h2        = (float*)(ws + OFF_H1);  // reuse: h1 dead after agg1

    // zero deg + cursor
    hipMemsetAsync(ws + OFF_DEG, 0, OFF_ROW - OFF_DEG, stream);

    const int nbE = (N_EDGES + 255) / 256;   // 3125
    const int nbN = (N_NODES + 255) / 256;   // 196

    count_deg_k<<<nbE, 256, 0, stream>>>(ei, deg);
    scan1_k<<<nbN, 256, 0, stream>>>(deg, row_start, bsums, dinv);
    scan2_k<<<1, 256, 0, stream>>>(bsums, nbN);
    scan3_k<<<nbN, 256, 0, stream>>>(row_start, bsums);
    fill_k<<<nbE, 256, 0, stream>>>(ei, row_start, cursor, csr_src);

    const int mBlocks = (N_NODES + 63) / 64;  // 782
    gemm_blds<128><<<dim3(mBlocks, 2), 256, 0, stream>>>(x, W1, h1, N_NODES);
    agg_k<128, true><<<(N_NODES + 3) / 4, 256, 0, stream>>>(h1, dinv, row_start, csr_src, b1, out1);
    gemm_blds<64><<<dim3(mBlocks, 1), 256, 0, stream>>>(out1, W2, h2, N_NODES);
    agg_k<64, false><<<(N_NODES + 3) / 4, 256, 0, stream>>>(h2, dinv, row_start, csr_src, b2, out);
}

// Round 10
// 240.282 us; speedup vs baseline: 3.9706x; 1.0161x over previous
//
#include <hip/hip_runtime.h>

// ---------------------------------------------------------------------------
// GCN 2-layer: out = A_n @ relu(A_n @ (x W1) + b1) W2 + b2,  A_n = D^-1/2 A D^-1/2
// N=50000 nodes, E=800000 edges (+ implicit self loops), F: 128 -> 128 -> 64.
// CSR by dst (count -> scan -> fill), dense fp32 GEMMs (B-in-LDS), wave-per-
// node gather:  out_v = d_v*(sum_e w_e h_s + d_v h_v) + b,  w_e = dinv[src].
// R8: agg 68us @3.2TB/s latency-bound (1 load in flight). R9: 4x MLP -> 58us
//   @3.75TB/s; still ~220cy/edge exposed latency.
// R10: (a) csr_w precomputed in fill_k kills the scattered dinv[s] gather on
//   the critical path; (b) 8-deep row-gather MLP.
// ---------------------------------------------------------------------------

#define N_NODES 50000
#define N_EDGES 800000

// workspace layout (bytes, all 256-aligned)
static constexpr size_t OFF_DEG  = 0;         // int[50000]
static constexpr size_t OFF_CUR  = 200192;    // int[50000]
static constexpr size_t OFF_ROW  = 400384;    // int[50001]
static constexpr size_t OFF_BS   = 600576;    // int[256]
static constexpr size_t OFF_DINV = 601600;    // float[50000]
static constexpr size_t OFF_CSR  = 801792;    // int[800000]
static constexpr size_t OFF_CSRW = 4001792;   // float[800000]
static constexpr size_t OFF_H1   = 7201792;   // float[50000*128]  (reused as h2)
static constexpr size_t OFF_OUT1 = 32801792;  // float[50000*128]
// total ~58.4 MB

__global__ __launch_bounds__(256) void count_deg_k(const int* __restrict__ ei,
                                                   int* __restrict__ deg) {
    int e = blockIdx.x * 256 + threadIdx.x;
    if (e < N_EDGES) {
        int d = ei[N_EDGES + e];
        if ((unsigned)d < N_NODES) atomicAdd(&deg[d], 1);
    }
}

// block-scan of deg -> row_start + per-block sums; also emits dinv.
__global__ __launch_bounds__(256) void scan1_k(const int* __restrict__ deg,
                                               int* __restrict__ row_start,
                                               int* __restrict__ bsums,
                                               float* __restrict__ dinv) {
    __shared__ int sm[256];
    int tid = threadIdx.x;
    int i = blockIdx.x * 256 + tid;
    int v = (i < N_NODES) ? deg[i] : 0;
    if (i < N_NODES) dinv[i] = rsqrtf((float)(v + 1));
    sm[tid] = v;
    __syncthreads();
    #pragma unroll
    for (int off = 1; off < 256; off <<= 1) {
        int t = (tid >= off) ? sm[tid - off] : 0;
        __syncthreads();
        sm[tid] += t;
        __syncthreads();
    }
    if (i < N_NODES) row_start[i] = sm[tid] - v;
    if (tid == 255) bsums[blockIdx.x] = sm[255];
}

__global__ __launch_bounds__(256) void scan2_k(int* __restrict__ bsums, int nb) {
    __shared__ int sm[256];
    int tid = threadIdx.x;
    int v = (tid < nb) ? bsums[tid] : 0;
    sm[tid] = v;
    __syncthreads();
    #pragma unroll
    for (int off = 1; off < 256; off <<= 1) {
        int t = (tid >= off) ? sm[tid - off] : 0;
        __syncthreads();
        sm[tid] += t;
        __syncthreads();
    }
    if (tid < nb) bsums[tid] = sm[tid] - v;  // exclusive block offsets
}

__global__ __launch_bounds__(256) void scan3_k(int* __restrict__ row_start,
                                               const int* __restrict__ bsums) {
    int i = blockIdx.x * 256 + threadIdx.x;
    if (i < N_NODES) row_start[i] += bsums[blockIdx.x];
    if (i == 0) row_start[N_NODES] = N_EDGES;
}

__global__ __launch_bounds__(256) void fill_k(const int* __restrict__ ei,
                                              const int* __restrict__ row_start,
                                              int* __restrict__ cursor,
                                              const float* __restrict__ dinv,
                                              int* __restrict__ csr_src,
                                              float* __restrict__ csr_w) {
    int e = blockIdx.x * 256 + threadIdx.x;
    if (e < N_EDGES) {
        int s = ei[e];
        int d = ei[N_EDGES + e];
        if ((unsigned)d < N_NODES && (unsigned)s < N_NODES) {
            int pos = row_start[d] + atomicAdd(&cursor[d], 1);
            if ((unsigned)pos < N_EDGES) {
                csr_src[pos] = s;
                csr_w[pos] = dinv[s];
            }
        }
    }
}

// ---------------------------------------------------------------------------
// fp32 GEMM with whole-B-in-LDS. C[M][N] = A[M][128] * B[128][N].
// Block: 256 threads, BM=64 rows x BN=64 cols. grid = (ceil(M/64), N/64).
// ---------------------------------------------------------------------------
template <int N>
__global__ __launch_bounds__(256, 4) void gemm_blds(const float* __restrict__ A,
                                                    const float* __restrict__ B,
                                                    float* __restrict__ C, int M) {
    constexpr int K = 128, BM = 64, BN = 64, PAD = 4;
    __shared__ float Bs[K][BN + PAD];   // 34816 B

    const int tid = threadIdx.x;
    const int nBase = blockIdx.y * BN;

    #pragma unroll
    for (int p = 0; p < 8; ++p) {
        int fi = tid + p * 256;
        int row = fi >> 4;            // 0..127
        int c4 = (fi & 15) * 4;       // 0..60
        float4 t = *(const float4*)&B[(size_t)row * N + nBase + c4];
        *(float4*)&Bs[row][c4] = t;
    }
    __syncthreads();

    const int tx = tid & 15, ty = tid >> 4;
    const int m0 = blockIdx.x * BM + ty * 4;
    const int n0 = tx * 4;

    const float* A0 = A + (size_t)(m0 + 0 < M ? m0 + 0 : M - 1) * K;
    const float* A1 = A + (size_t)(m0 + 1 < M ? m0 + 1 : M - 1) * K;
    const float* A2 = A + (size_t)(m0 + 2 < M ? m0 + 2 : M - 1) * K;
    const float* A3 = A + (size_t)(m0 + 3 < M ? m0 + 3 : M - 1) * K;

    float acc[4][4] = {};

    #pragma unroll 4
    for (int kq = 0; kq < K / 4; ++kq) {
        float4 a0 = *(const float4*)&A0[kq * 4];
        float4 a1 = *(const float4*)&A1[kq * 4];
        float4 a2 = *(const float4*)&A2[kq * 4];
        float4 a3 = *(const float4*)&A3[kq * 4];
        #pragma unroll
        for (int kk = 0; kk < 4; ++kk) {
            int k = kq * 4 + kk;
            float4 bv = *(const float4*)&Bs[k][n0];
            float av0 = kk == 0 ? a0.x : kk == 1 ? a0.y : kk == 2 ? a0.z : a0.w;
            float av1 = kk == 0 ? a1.x : kk == 1 ? a1.y : kk == 2 ? a1.z : a1.w;
            float av2 = kk == 0 ? a2.x : kk == 1 ? a2.y : kk == 2 ? a2.z : a2.w;
            float av3 = kk == 0 ? a3.x : kk == 1 ? a3.y : kk == 2 ? a3.z : a3.w;
            acc[0][0] = fmaf(av0, bv.x, acc[0][0]);
            acc[0][1] = fmaf(av0, bv.y, acc[0][1]);
            acc[0][2] = fmaf(av0, bv.z, acc[0][2]);
            acc[0][3] = fmaf(av0, bv.w, acc[0][3]);
            acc[1][0] = fmaf(av1, bv.x, acc[1][0]);
            acc[1][1] = fmaf(av1, bv.y, acc[1][1]);
            acc[1][2] = fmaf(av1, bv.z, acc[1][2]);
            acc[1][3] = fmaf(av1, bv.w, acc[1][3]);
            acc[2][0] = fmaf(av2, bv.x, acc[2][0]);
            acc[2][1] = fmaf(av2, bv.y, acc[2][1]);
            acc[2][2] = fmaf(av2, bv.z, acc[2][2]);
            acc[2][3] = fmaf(av2, bv.w, acc[2][3]);
            acc[3][0] = fmaf(av3, bv.x, acc[3][0]);
            acc[3][1] = fmaf(av3, bv.y, acc[3][1]);
            acc[3][2] = fmaf(av3, bv.z, acc[3][2]);
            acc[3][3] = fmaf(av3, bv.w, acc[3][3]);
        }
    }

    #pragma unroll
    for (int i = 0; i < 4; ++i) {
        int row = blockIdx.x * BM + ty * 4 + i;
        if (row < M) {
            *(float4*)&C[(size_t)row * N + nBase + n0] =
                make_float4(acc[i][0], acc[i][1], acc[i][2], acc[i][3]);
        }
    }
}

// ---------------------------------------------------------------------------
// Aggregation: one wave (64 lanes) per node; csr_w read coalesced (no
// scattered dinv gather); 8 independent row-gathers in flight.
// out_v = d_v * (sum_edges w_e * h_s + d_v * h_v) + bias  [, relu]
// ---------------------------------------------------------------------------
template <int F, bool RELU>
__global__ __launch_bounds__(256) void agg_k(const float* __restrict__ h,
                                             const float* __restrict__ dinv,
                                             const int* __restrict__ row_start,
                                             const int* __restrict__ csr_src,
                                             const float* __restrict__ csr_w,
                                             const float* __restrict__ bias,
                                             float* __restrict__ out) {
    constexpr int VEC = F / 64;  // 2 or 1
    int wid = (blockIdx.x * 256 + threadIdx.x) >> 6;
    int lane = threadIdx.x & 63;
    if (wid >= N_NODES) return;
    int v = wid;
    float dv = dinv[v];

    const float* hL = h + (size_t)lane * VEC;  // lane-offset base

    float acc0, acc1 = 0.f;
    {
        const float* hv = hL + (size_t)v * F;
        if constexpr (VEC == 2) {
            float2 t = *(const float2*)hv;
            acc0 = dv * t.x; acc1 = dv * t.y;
        } else {
            acc0 = dv * hv[0];
        }
    }

    int e0 = row_start[v], e1 = row_start[v + 1];
    for (int e = e0; e < e1; e += 64) {
        int cnt = min(64, e1 - e);
        int s = 0; float w = 0.f;
        if (lane < cnt) { s = csr_src[e + lane]; w = csr_w[e + lane]; }
        int j = 0;
        for (; j + 8 <= cnt; j += 8) {
            int   ss0 = __shfl(s, j + 0), ss1 = __shfl(s, j + 1),
                  ss2 = __shfl(s, j + 2), ss3 = __shfl(s, j + 3),
                  ss4 = __shfl(s, j + 4), ss5 = __shfl(s, j + 5),
                  ss6 = __shfl(s, j + 6), ss7 = __shfl(s, j + 7);
            float ww0 = __shfl(w, j + 0), ww1 = __shfl(w, j + 1),
                  ww2 = __shfl(w, j + 2), ww3 = __shfl(w, j + 3),
                  ww4 = __shfl(w, j + 4), ww5 = __shfl(w, j + 5),
                  ww6 = __shfl(w, j + 6), ww7 = __shfl(w, j + 7);
            if constexpr (VEC == 2) {
                float2 t0 = *(const float2*)&hL[(size_t)ss0 * F];
                float2 t1 = *(const float2*)&hL[(size_t)ss1 * F];
                float2 t2 = *(const float2*)&hL[(size_t)ss2 * F];
                float2 t3 = *(const float2*)&hL[(size_t)ss3 * F];
                float2 t4 = *(const float2*)&hL[(size_t)ss4 * F];
                float2 t5 = *(const float2*)&hL[(size_t)ss5 * F];
                float2 t6 = *(const float2*)&hL[(size_t)ss6 * F];
                float2 t7 = *(const float2*)&hL[(size_t)ss7 * F];
                acc0 = fmaf(ww0, t0.x, acc0); acc1 = fmaf(ww0, t0.y, acc1);
                acc0 = fmaf(ww1, t1.x, acc0); acc1 = fmaf(ww1, t1.y, acc1);
                acc0 = fmaf(ww2, t2.x, acc0); acc1 = fmaf(ww2, t2.y, acc1);
                acc0 = fmaf(ww3, t3.x, acc0); acc1 = fmaf(ww3, t3.y, acc1);
                acc0 = fmaf(ww4, t4.x, acc0); acc1 = fmaf(ww4, t4.y, acc1);
                acc0 = fmaf(ww5, t5.x, acc0); acc1 = fmaf(ww5, t5.y, acc1);
                acc0 = fmaf(ww6, t6.x, acc0); acc1 = fmaf(ww6, t6.y, acc1);
                acc0 = fmaf(ww7, t7.x, acc0); acc1 = fmaf(ww7, t7.y, acc1);
            } else {
                float t0 = hL[(size_t)ss0 * F];
                float t1 = hL[(size_t)ss1 * F];
                float t2 = hL[(size_t)ss2 * F];
                float t3 = hL[(size_t)ss3 * F];
                float t4 = hL[(size_t)ss4 * F];
                float t5 = hL[(size_t)ss5 * F];
                float t6 = hL[(size_t)ss6 * F];
                float t7 = hL[(size_t)ss7 * F];
                acc0 = fmaf(ww0, t0, acc0);
                acc0 = fmaf(ww1, t1, acc0);
                acc0 = fmaf(ww2, t2, acc0);
                acc0 = fmaf(ww3, t3, acc0);
                acc0 = fmaf(ww4, t4, acc0);
                acc0 = fmaf(ww5, t5, acc0);
                acc0 = fmaf(ww6, t6, acc0);
                acc0 = fmaf(ww7, t7, acc0);
            }
        }
        for (; j + 4 <= cnt; j += 4) {
            int   ss0 = __shfl(s, j + 0), ss1 = __shfl(s, j + 1),
                  ss2 = __shfl(s, j + 2), ss3 = __shfl(s, j + 3);
            float ww0 = __shfl(w, j + 0), ww1 = __shfl(w, j + 1),
                  ww2 = __shfl(w, j + 2), ww3 = __shfl(w, j + 3);
            if constexpr (VEC == 2) {
                float2 t0 = *(const float2*)&hL[(size_t)ss0 * F];
                float2 t1 = *(const float2*)&hL[(size_t)ss1 * F];
                float2 t2 = *(const float2*)&hL[(size_t)ss2 * F];
                float2 t3 = *(const float2*)&hL[(size_t)ss3 * F];
                acc0 = fmaf(ww0, t0.x, acc0); acc1 = fmaf(ww0, t0.y, acc1);
                acc0 = fmaf(ww1, t1.x, acc0); acc1 = fmaf(ww1, t1.y, acc1);
                acc0 = fmaf(ww2, t2.x, acc0); acc1 = fmaf(ww2, t2.y, acc1);
                acc0 = fmaf(ww3, t3.x, acc0); acc1 = fmaf(ww3, t3.y, acc1);
            } else {
                float t0 = hL[(size_t)ss0 * F];
                float t1 = hL[(size_t)ss1 * F];
                float t2 = hL[(size_t)ss2 * F];
                float t3 = hL[(size_t)ss3 * F];
                acc0 = fmaf(ww0, t0, acc0);
                acc0 = fmaf(ww1, t1, acc0);
                acc0 = fmaf(ww2, t2, acc0);
                acc0 = fmaf(ww3, t3, acc0);
            }
        }
        for (; j < cnt; ++j) {
            int ss = __shfl(s, j);
            float ww = __shfl(w, j);
            if constexpr (VEC == 2) {
                float2 t = *(const float2*)&hL[(size_t)ss * F];
                acc0 = fmaf(ww, t.x, acc0); acc1 = fmaf(ww, t.y, acc1);
            } else {
                acc0 = fmaf(ww, hL[(size_t)ss * F], acc0);
            }
        }
    }

    if constexpr (VEC == 2) {
        float o0 = dv * acc0 + bias[lane * 2];
        float o1 = dv * acc1 + bias[lane * 2 + 1];
        if (RELU) { o0 = fmaxf(o0, 0.f); o1 = fmaxf(o1, 0.f); }
        *(float2*)&out[(size_t)v * F + lane * 2] = make_float2(o0, o1);
    } else {
        float o0 = dv * acc0 + bias[lane];
        if (RELU) o0 = fmaxf(o0, 0.f);
        out[(size_t)v * F + lane] = o0;
    }
}

extern "C" void kernel_launch(void* const* d_in, const int* in_sizes, int n_in,
                              void* d_out, int out_size, void* d_ws, size_t ws_size,
                              hipStream_t stream) {
    const float* x        = (const float*)d_in[0];   // [50000,128]
    const float* W1       = (const float*)d_in[1];   // [128,128]
    const float* b1       = (const float*)d_in[2];   // [128]
    const float* W2       = (const float*)d_in[3];   // [128,64]
    const float* b2       = (const float*)d_in[4];   // [64]
    const int*   ei       = (const int*)d_in[5];     // [2,800000] delivered as int32
    float* out = (float*)d_out;                      // [50000,64]

    char* ws = (char*)d_ws;
    int*   deg       = (int*)(ws + OFF_DEG);
    int*   cursor    = (int*)(ws + OFF_CUR);
    int*   row_start = (int*)(ws + OFF_ROW);
    int*   bsums     = (int*)(ws + OFF_BS);
    float* dinv      = (float*)(ws + OFF_DINV);
    int*   csr_src   = (int*)(ws + OFF_CSR);
    float* csr_w     = (float*)(ws + OFF_CSRW);
    float* h1        = (float*)(ws + OFF_H1);
    float* out1      = (float*)(ws + OFF_OUT1);
    float* h2        = (float*)(ws + OFF_H1);  // reuse: h1 dead after agg1

    // zero deg + cursor
    hipMemsetAsync(ws + OFF_DEG, 0, OFF_ROW - OFF_DEG, stream);

    const int nbE = (N_EDGES + 255) / 256;   // 3125
    const int nbN = (N_NODES + 255) / 256;   // 196

    count_deg_k<<<nbE, 256, 0, stream>>>(ei, deg);
    scan1_k<<<nbN, 256, 0, stream>>>(deg, row_start, bsums, dinv);
    scan2_k<<<1, 256, 0, stream>>>(bsums, nbN);
    scan3_k<<<nbN, 256, 0, stream>>>(row_start, bsums);
    fill_k<<<nbE, 256, 0, stream>>>(ei, row_start, cursor, dinv, csr_src, csr_w);

    const int mBlocks = (N_NODES + 63) / 64;  // 782
    gemm_blds<128><<<dim3(mBlocks, 2), 256, 0, stream>>>(x, W1, h1, N_NODES);
    agg_k<128, true><<<(N_NODES + 3) / 4, 256, 0, stream>>>(h1, dinv, row_start, csr_src, csr_w, b1, out1);
    gemm_blds<64><<<dim3(mBlocks, 1), 256, 0, stream>>>(out1, W2, h2, N_NODES);
    agg_k<64, false><<<(N_NODES + 3) / 4, 256, 0, stream>>>(h2, dinv, row_start, csr_src, csr_w, b2, out);
}